// Round 7
// baseline (142.052 us; speedup 1.0000x reference)
//
#include <hip/hip_runtime.h>
#include <hip/hip_fp16.h>
#include <stdint.h>

#define LN_EPS 1e-5f
#define GN_EPS 1e-5f

// Edge packing: (src << 16) | dst — valid because N = 50000 < 65536.
#define NSB 64        // pass-1 bins: dst>>10 (1024 nodes); 49 used at N=50000
#define BE1 2048      // edges per radix block
#define CAP1R 88      // per (block,bin) region cap (mean 42, +7.2 sigma)
#define RPC 22        // regions per part2 chunk (22*88=1936 <= 2048 stage)
#define CH2 18        // part2 chunks per super-bucket (18*22 >= 391 regions)
#define NPB2 32       // nodes per final bucket
#define SLAB2 768     // final bucket capacity (mean 510, +11 sigma)
#define NFBA 2048     // final-bucket allocation (1568 used)
#define CAP2 768
#define NSLOT 16      // GN accumulation slots

// ---------- K1: merged {regioned radix pass 1} ∥ {x->fp16} ∥ {zero ws} ------
// No global cursors: block b writes bin sb's run into fixed region
// pairs1[(b*NSB+sb)*CAP1R .. +count), count -> counts1[sb*PB1+b] (transposed
// for coalesced reads in k_part2). Block PB1 also zeroes cursors2+accum.
__global__ __launch_bounds__(512) void k_sort1_half(
    const uint32_t* __restrict__ ew, int E, int PB1,
    const float* __restrict__ x, uint4* __restrict__ xh8, int n8,
    int* __restrict__ zbase, int nz, int* __restrict__ counts1,
    uint32_t* __restrict__ pairs1) {
  __shared__ int whist[8 * NSB];
  __shared__ int wbase[8 * NSB];
  __shared__ int wlcur[8 * NSB];
  __shared__ int binStart[NSB];
  __shared__ uint32_t stage[BE1];  // 8KB
  const int t = threadIdx.x;

  if (blockIdx.x >= PB1) {  // ---- fp16-convert role ----
    if (blockIdx.x == PB1) {  // zero cursors2+accum (stream-ordered vs users)
      for (int i = t; i < nz; i += 512) zbase[i] = 0;
    }
    int i = (blockIdx.x - PB1) * 512 + t;
    if (i >= n8) return;
    float4 a = *(const float4*)&x[i * 8];
    float4 b = *(const float4*)&x[i * 8 + 4];
    __half2 h0 = __floats2half2_rn(a.x, a.y);
    __half2 h1 = __floats2half2_rn(a.z, a.w);
    __half2 h2 = __floats2half2_rn(b.x, b.y);
    __half2 h3 = __floats2half2_rn(b.z, b.w);
    uint4 o;
    o.x = *(uint32_t*)&h0; o.y = *(uint32_t*)&h1;
    o.z = *(uint32_t*)&h2; o.w = *(uint32_t*)&h3;
    xh8[i] = o;
    return;
  }

  // ---- radix pass-1 role ----
  const int b = blockIdx.x;
  const int w = t >> 6;
  const int e0 = b * BE1;
  const int cnt = min(BE1, E - e0);

  // Sampled dtype detect (512 odd dwords): int64 high words are always 0;
  // int32 payload (random node ids) is ~surely nonzero across 512 samples.
  uint32_t v = 0;
  if (t < cnt) v = ew[2 * (e0 + t) + 1];
  const int is32 = __syncthreads_or((int)(v != 0));

  whist[t] = 0;  // 8*NSB == 512 == blockDim
  wlcur[t] = 0;
  __syncthreads();

  uint32_t myP[4];
  #pragma unroll
  for (int r = 0; r < 4; ++r) {
    int i = t + 512 * r;
    if (i < cnt) {
      long long e = e0 + i;
      int s, d;
      if (is32) {
        s = ((const int*)ew)[e];
        d = ((const int*)ew)[(long long)E + e];
      } else {
        s = (int)((const long long*)ew)[e];
        d = (int)((const long long*)ew)[(long long)E + e];
      }
      myP[r] = ((uint32_t)s << 16) | (uint32_t)d;
      atomicAdd(&whist[w * NSB + (d >> 10)], 1);
    }
  }
  __syncthreads();

  if (t < NSB) {  // bin t: prefix over 8 waves, then wave-wide shfl scan
    int sum = 0;
    #pragma unroll
    for (int w2 = 0; w2 < 8; ++w2) {
      wbase[w2 * NSB + t] = sum;
      sum += whist[w2 * NSB + t];
    }
    int s = sum;
    #pragma unroll
    for (int d = 1; d < NSB; d <<= 1) {
      int o = __shfl_up(s, d, 64);
      if (t >= d) s += o;
    }
    binStart[t] = s - sum;
    counts1[t * PB1 + b] = sum;  // transposed: [bin][block]
  }
  __syncthreads();

  #pragma unroll
  for (int r = 0; r < 4; ++r) {
    int i = t + 512 * r;
    if (i < cnt) {
      int b2 = (int)(myP[r] & 0xFFFFu) >> 10;
      int p = binStart[b2] + wbase[w * NSB + b2] +
              atomicAdd(&wlcur[w * NSB + b2], 1);
      stage[p] = myP[r];
    }
  }
  __syncthreads();

  // coalesced write-out into fixed regions: ~42-edge runs per bin
  for (int i = t; i < cnt; i += 512) {
    uint32_t pr = stage[i];
    int sb = (int)(pr & 0xFFFFu) >> 10;
    int rel = i - binStart[sb];
    if (rel < CAP1R) pairs1[((size_t)b * NSB + sb) * CAP1R + rel] = pr;
  }
}

// ------ K2: radix pass 2 (regioned input) -> 32-node final buckets ----------
// Block = (sb, chunk of RPC regions). Scans its ~1900 edges ONCE (round-5
// lesson: x32-redundant scan in k_fused cost +40us), ranks into 32 sub-bins,
// scatters to pairs2 with atomic cursors2 bases.
__global__ __launch_bounds__(512) void k_part2(
    const uint32_t* __restrict__ pairs1, const int* __restrict__ counts1,
    int PB1, int* cursors2, uint32_t* pairs2) {
  __shared__ int whist[8 * 32];
  __shared__ int wbase[8 * 32];
  __shared__ int wlcur[8 * 32];
  __shared__ int binStart[32], baseG[32];
  __shared__ int cLDS[RPC];
  __shared__ int totLDS;
  __shared__ uint32_t stage[BE1];  // 8KB
  const int t = threadIdx.x;
  const int w = t >> 6;
  const int sb = blockIdx.x / CH2;
  const int ch = blockIdx.x % CH2;
  const int r0 = ch * RPC;
  const int nr = min(RPC, PB1 - r0);

  if (t < 8 * 32) { whist[t] = 0; wlcur[t] = 0; }
  if (t < nr) cLDS[t] = counts1[sb * PB1 + r0 + t];
  __syncthreads();

  // flattened slot space RPC*CAP1R; valid slots loaded, hist by sub-bin
  uint32_t myP[4];
  int myV[4];
  #pragma unroll
  for (int r = 0; r < 4; ++r) {
    int i = t + 512 * r;
    myV[r] = 0;
    if (i < nr * CAP1R) {
      int reg = i / CAP1R, idx = i % CAP1R;
      if (idx < cLDS[reg]) {
        myP[r] = pairs1[((size_t)(r0 + reg) * NSB + sb) * CAP1R + idx];
        myV[r] = 1;
        atomicAdd(&whist[(w << 5) + ((myP[r] >> 5) & 31)], 1);
      }
    }
  }
  __syncthreads();

  if (t < 32) {  // prefix over 8 waves then shfl scan over 32 bins
    int sum = 0;
    #pragma unroll
    for (int w2 = 0; w2 < 8; ++w2) {
      wbase[(w2 << 5) + t] = sum;
      sum += whist[(w2 << 5) + t];
    }
    int s = sum;
    #pragma unroll
    for (int d = 1; d < 32; d <<= 1) {
      int o = __shfl_up(s, d, 32);
      if (t >= d) s += o;
    }
    binStart[t] = s - sum;
    baseG[t] = (sum > 0) ? atomicAdd(&cursors2[(sb << 5) + t], sum) : 0;
    if (t == 31) totLDS = s;  // total valid edges this chunk
  }
  __syncthreads();

  #pragma unroll
  for (int r = 0; r < 4; ++r) {
    if (myV[r]) {
      int b2 = (int)(myP[r] >> 5) & 31;
      int p = binStart[b2] + wbase[(w << 5) + b2] +
              atomicAdd(&wlcur[(w << 5) + b2], 1);
      stage[p] = myP[r];
    }
  }
  __syncthreads();

  const int total = totLDS;
  for (int i = t; i < total; i += 512) {
    uint32_t pr = stage[i];
    int sub = (int)(pr >> 5) & 31;
    int o = baseG[sub] + (i - binStart[sub]);
    if (o < SLAB2) pairs2[(size_t)((sb << 5) + sub) * SLAB2 + o] = pr;
  }
}

// ---------------- K3: fused sort + fp16-gather + MLP x2 + GN partials -------
// Block = 256 thr owns 32 nodes. GEMM restructured (round-6 analysis: GEMM is
// LDS-issue-bound, 23.5us aggregate at 2n x 4c): HYt is node-major [32][68],
// GEMM runs on 128 threads at 4n x 4c = per 4-k step 8x ds_read_b128 for 64
// FMA (1.5 LDS-cyc/FMA vs 2.25) -> ~15.7us aggregate. LDS total unchanged.
__global__ __launch_bounds__(256, 6) void k_fused(
    const float4* __restrict__ x4, const uint4* __restrict__ xh8,
    const uint32_t* __restrict__ pairs, const int* __restrict__ cursors,
    const float* __restrict__ W0g, const float* __restrict__ ln0w,
    const float* __restrict__ ln0b, const float* __restrict__ W1g,
    const float* __restrict__ ln1w, const float* __restrict__ ln1b,
    float* __restrict__ out, int N, float* __restrict__ accum) {
  __shared__ __align__(16) float HYt[32 * 68];  // h node-major; then y1
  __shared__ __align__(16) float U[2048];       // 8KB phase union
  int* hist = (int*)U;            // [32]
  int* offs = hist + 32;          // [32]
  int* lcur = offs + 32;          // [32]
  int* list = lcur + 32;          // [CAP2] (total 3.5KB < 8KB)
  float* Wt = U;                  // [2048] = 32 k-rows x 64 c
  float* wsum = U;                // [256] (2 waves x 128)

  const int t = threadIdx.x;
  const int B = blockIdx.x;
  const int cnt = min(cursors[B], SLAB2);
  const uint32_t* pb = pairs + (size_t)B * SLAB2;
  const int node0 = B * NPB2;

  if (t < 32) hist[t] = 0;
  __syncthreads();

  for (int i = t; i < cnt; i += 256) atomicAdd(&hist[pb[i] & 31], 1);
  __syncthreads();

  if (t < 32) {  // shfl scan over 32 bins
    int v = hist[t], s = v;
    #pragma unroll
    for (int d = 1; d < 32; d <<= 1) {
      int o = __shfl_up(s, d, 32);
      if (t >= d) s += o;
    }
    offs[t] = s - v;
    lcur[t] = s - v;
  }
  __syncthreads();

  for (int i = t; i < cnt; i += 256) {
    uint32_t p = pb[i];
    int pos = atomicAdd(&lcur[p & 31], 1);
    if (pos < CAP2) list[pos] = (int)(p >> 16);
  }
  __syncthreads();

  // gather: 8 lanes/node (q8 = channel octet), fp32 self + fp16 neighbors
  const int q8 = t & 7;
  const int nl = t >> 3;  // 0..31
  const int node = node0 + nl;
  float acc[8] = {};
  if (node < N) {
    float4 sa = x4[node * 16 + 2 * q8];
    float4 sb = x4[node * 16 + 2 * q8 + 1];
    acc[0] = sa.x; acc[1] = sa.y; acc[2] = sa.z; acc[3] = sa.w;
    acc[4] = sb.x; acc[5] = sb.y; acc[6] = sb.z; acc[7] = sb.w;
    int j = offs[nl];
    const int e = min(lcur[nl], CAP2);
    for (; j + 3 < e; j += 4) {
      uint4 v0 = xh8[list[j] * 8 + q8];
      uint4 v1 = xh8[list[j + 1] * 8 + q8];
      uint4 v2 = xh8[list[j + 2] * 8 + q8];
      uint4 v3 = xh8[list[j + 3] * 8 + q8];
      #pragma unroll
      for (int c = 0; c < 4; ++c) {
        uint32_t u0 = (&v0.x)[c], u1 = (&v1.x)[c];
        uint32_t u2 = (&v2.x)[c], u3 = (&v3.x)[c];
        float2 f0 = __half22float2(*(__half2*)&u0);
        float2 f1 = __half22float2(*(__half2*)&u1);
        float2 f2 = __half22float2(*(__half2*)&u2);
        float2 f3 = __half22float2(*(__half2*)&u3);
        acc[2 * c]     += (f0.x + f1.x) + (f2.x + f3.x);
        acc[2 * c + 1] += (f0.y + f1.y) + (f2.y + f3.y);
      }
    }
    for (; j < e; ++j) {
      uint4 v0 = xh8[list[j] * 8 + q8];
      #pragma unroll
      for (int c = 0; c < 4; ++c) {
        uint32_t u0 = (&v0.x)[c];
        float2 f0 = __half22float2(*(__half2*)&u0);
        acc[2 * c] += f0.x;
        acc[2 * c + 1] += f0.y;
      }
    }
  }
  __syncthreads();  // sort scratch (incl. list) dead from here

  // deposit h node-major: HYt[nl][8q8..8q8+7] = 2x b128 stores
  *(float4*)&HYt[nl * 68 + 8 * q8] = make_float4(acc[0], acc[1], acc[2], acc[3]);
  *(float4*)&HYt[nl * 68 + 8 * q8 + 4] = make_float4(acc[4], acc[5], acc[6], acc[7]);

  const int tx = t & 15;   // ch quad: 4tx..4tx+3
  const int ty8 = t >> 4;  // node quad 4*ty8 (active t<128 -> ty8 0..7)
  const int wc = t & 63, ww = t >> 6;  // W staging coords
  const bool act = t < 128;
  float a0[4][4] = {};

  #pragma unroll
  for (int half = 0; half < 2; ++half) {
    {  // stage W0^T k-half [32*half, 32*half+32) (all 256 threads)
      #pragma unroll
      for (int r = 0; r < 2; ++r) {
        int k4 = ww * 4 + 16 * r;  // 0..28
        float4 v = *(const float4*)&W0g[wc * 64 + 32 * half + k4];
        Wt[(k4 + 0) * 64 + wc] = v.x; Wt[(k4 + 1) * 64 + wc] = v.y;
        Wt[(k4 + 2) * 64 + wc] = v.z; Wt[(k4 + 3) * 64 + wc] = v.w;
      }
    }
    __syncthreads();
    if (act) {
      #pragma unroll 2
      for (int k4 = 0; k4 < 8; ++k4) {
        float4 h0 = *(const float4*)&HYt[(4 * ty8 + 0) * 68 + 32 * half + 4 * k4];
        float4 h1 = *(const float4*)&HYt[(4 * ty8 + 1) * 68 + 32 * half + 4 * k4];
        float4 h2 = *(const float4*)&HYt[(4 * ty8 + 2) * 68 + 32 * half + 4 * k4];
        float4 h3 = *(const float4*)&HYt[(4 * ty8 + 3) * 68 + 32 * half + 4 * k4];
        #pragma unroll
        for (int j = 0; j < 4; ++j) {
          float4 wv = *(const float4*)&Wt[(4 * k4 + j) * 64 + 4 * tx];
          float hj0 = (&h0.x)[j], hj1 = (&h1.x)[j];
          float hj2 = (&h2.x)[j], hj3 = (&h3.x)[j];
          a0[0][0] += hj0 * wv.x; a0[0][1] += hj0 * wv.y;
          a0[0][2] += hj0 * wv.z; a0[0][3] += hj0 * wv.w;
          a0[1][0] += hj1 * wv.x; a0[1][1] += hj1 * wv.y;
          a0[1][2] += hj1 * wv.z; a0[1][3] += hj1 * wv.w;
          a0[2][0] += hj2 * wv.x; a0[2][1] += hj2 * wv.y;
          a0[2][2] += hj2 * wv.z; a0[2][3] += hj2 * wv.w;
          a0[3][0] += hj3 * wv.x; a0[3][1] += hj3 * wv.y;
          a0[3][2] += hj3 * wv.z; a0[3][3] += hj3 * wv.w;
        }
      }
    }
    __syncthreads();  // Wt reads done before restage; HYt reads done
  }

  // ---- layer-1 LN + ReLU; y1 (node-major) back into HYt ----
  if (act) {
    const float4 lw = *(const float4*)&ln0w[4 * tx];
    const float4 lb = *(const float4*)&ln0b[4 * tx];
    #pragma unroll
    for (int j = 0; j < 4; ++j) {
      float s = a0[j][0] + a0[j][1] + a0[j][2] + a0[j][3];
      #pragma unroll
      for (int m = 1; m < 16; m <<= 1) s += __shfl_xor(s, m, 16);
      float mu = s * (1.f / 64.f);
      float d0 = a0[j][0] - mu, d1 = a0[j][1] - mu;
      float d2 = a0[j][2] - mu, d3 = a0[j][3] - mu;
      float vv = d0 * d0 + d1 * d1 + d2 * d2 + d3 * d3;
      #pragma unroll
      for (int m = 1; m < 16; m <<= 1) vv += __shfl_xor(vv, m, 16);
      float rs = rsqrtf(vv * (1.f / 64.f) + LN_EPS);
      *(float4*)&HYt[(4 * ty8 + j) * 68 + 4 * tx] = make_float4(
          fmaxf(d0 * rs * lw.x + lb.x, 0.f), fmaxf(d1 * rs * lw.y + lb.y, 0.f),
          fmaxf(d2 * rs * lw.z + lb.z, 0.f), fmaxf(d3 * rs * lw.w + lb.w, 0.f));
    }
  }
  // no barrier needed here: GEMM2's first post-stage barrier orders y1 writes

  float a1[4][4] = {};
  #pragma unroll
  for (int half = 0; half < 2; ++half) {
    {  // stage W1^T k-half (all 256 threads; U no longer read as W0)
      #pragma unroll
      for (int r = 0; r < 2; ++r) {
        int k4 = ww * 4 + 16 * r;
        float4 v = *(const float4*)&W1g[wc * 64 + 32 * half + k4];
        Wt[(k4 + 0) * 64 + wc] = v.x; Wt[(k4 + 1) * 64 + wc] = v.y;
        Wt[(k4 + 2) * 64 + wc] = v.z; Wt[(k4 + 3) * 64 + wc] = v.w;
      }
    }
    __syncthreads();
    if (act) {
      #pragma unroll 2
      for (int k4 = 0; k4 < 8; ++k4) {
        float4 h0 = *(const float4*)&HYt[(4 * ty8 + 0) * 68 + 32 * half + 4 * k4];
        float4 h1 = *(const float4*)&HYt[(4 * ty8 + 1) * 68 + 32 * half + 4 * k4];
        float4 h2 = *(const float4*)&HYt[(4 * ty8 + 2) * 68 + 32 * half + 4 * k4];
        float4 h3 = *(const float4*)&HYt[(4 * ty8 + 3) * 68 + 32 * half + 4 * k4];
        #pragma unroll
        for (int j = 0; j < 4; ++j) {
          float4 wv = *(const float4*)&Wt[(4 * k4 + j) * 64 + 4 * tx];
          float hj0 = (&h0.x)[j], hj1 = (&h1.x)[j];
          float hj2 = (&h2.x)[j], hj3 = (&h3.x)[j];
          a1[0][0] += hj0 * wv.x; a1[0][1] += hj0 * wv.y;
          a1[0][2] += hj0 * wv.z; a1[0][3] += hj0 * wv.w;
          a1[1][0] += hj1 * wv.x; a1[1][1] += hj1 * wv.y;
          a1[1][2] += hj1 * wv.z; a1[1][3] += hj1 * wv.w;
          a1[2][0] += hj2 * wv.x; a1[2][1] += hj2 * wv.y;
          a1[2][2] += hj2 * wv.z; a1[2][3] += hj2 * wv.w;
          a1[3][0] += hj3 * wv.x; a1[3][1] += hj3 * wv.y;
          a1[3][2] += hj3 * wv.z; a1[3][3] += hj3 * wv.w;
        }
      }
    }
    __syncthreads();
  }

  // ---- layer-2 LN + ReLU + store h + GraphNorm partials (t<128) ----
  float st1[4] = {0.f, 0.f, 0.f, 0.f}, st2[4] = {0.f, 0.f, 0.f, 0.f};
  if (act) {
    const float4 lw = *(const float4*)&ln1w[4 * tx];
    const float4 lb = *(const float4*)&ln1b[4 * tx];
    #pragma unroll
    for (int j = 0; j < 4; ++j) {
      int nodej = node0 + 4 * ty8 + j;
      float s = a1[j][0] + a1[j][1] + a1[j][2] + a1[j][3];
      #pragma unroll
      for (int m = 1; m < 16; m <<= 1) s += __shfl_xor(s, m, 16);
      float mu = s * (1.f / 64.f);
      float d0 = a1[j][0] - mu, d1 = a1[j][1] - mu;
      float d2 = a1[j][2] - mu, d3 = a1[j][3] - mu;
      float vv = d0 * d0 + d1 * d1 + d2 * d2 + d3 * d3;
      #pragma unroll
      for (int m = 1; m < 16; m <<= 1) vv += __shfl_xor(vv, m, 16);
      float rs = rsqrtf(vv * (1.f / 64.f) + LN_EPS);
      float y0 = fmaxf(d0 * rs * lw.x + lb.x, 0.f);
      float y1 = fmaxf(d1 * rs * lw.y + lb.y, 0.f);
      float y2 = fmaxf(d2 * rs * lw.z + lb.z, 0.f);
      float y3 = fmaxf(d3 * rs * lw.w + lb.w, 0.f);
      if (nodej < N) {
        *(float4*)&out[(long long)nodej * 64 + 4 * tx] =
            make_float4(y0, y1, y2, y3);
        st1[0] += y0; st2[0] += y0 * y0;
        st1[1] += y1; st2[1] += y1 * y1;
        st1[2] += y2; st2[2] += y2 * y2;
        st1[3] += y3; st2[3] += y3 * y3;
      }
    }
    #pragma unroll
    for (int i = 0; i < 4; ++i) {
      st1[i] += __shfl_xor(st1[i], 16, 64);
      st1[i] += __shfl_xor(st1[i], 32, 64);
      st2[i] += __shfl_xor(st2[i], 16, 64);
      st2[i] += __shfl_xor(st2[i], 32, 64);
    }
  }
  // last __syncthreads above separates Wt reads; wsum aliases U now
  const int lane = t & 63, w = t >> 6;
  if (act && lane < 16) {
    #pragma unroll
    for (int i = 0; i < 4; ++i) {
      wsum[w * 128 + 4 * lane + i] = st1[i];
      wsum[w * 128 + 64 + 4 * lane + i] = st2[i];
    }
  }
  __syncthreads();
  if (t < 128) {
    float s = wsum[t] + wsum[128 + t];
    // slotted device-scope accumulation; visibility via stream order
    atomicAdd(&accum[(B & (NSLOT - 1)) * 128 + t], s);
  }
}

// -------- K4: per-block ab = f(slot sums) (L2-resident), then apply ---------
__global__ __launch_bounds__(256) void k_apply(
    const float4* __restrict__ h4, const float* __restrict__ accum,
    const float* __restrict__ alpha, const float* __restrict__ gnw,
    const float* __restrict__ gnb, float4* __restrict__ outp, int N) {
  __shared__ float cs[128];  // column sums: [0..63]=Σy, [64..127]=Σy²
  __shared__ float ab[128];  // [0..63]=a, [64..127]=b
  const int t = threadIdx.x;
  if (t < 128) {
    float s = 0.f;
    #pragma unroll
    for (int sl = 0; sl < NSLOT; ++sl) s += accum[sl * 128 + t];
    cs[t] = s;
  }
  __syncthreads();
  if (t < 64) {
    float invN = 1.f / (float)N;
    float mu = cs[t] * invN;
    float e2 = cs[64 + t] * invN;
    float al = alpha[t];
    float var = e2 - 2.f * al * mu * mu + al * al * mu * mu;
    float a = gnw[t] * rsqrtf(var + GN_EPS);
    ab[t] = a;
    ab[64 + t] = gnb[t] - a * al * mu;
  }
  __syncthreads();
  int idx = blockIdx.x * 256 + t;
  if (idx < N * 16) {
    int q = idx & 15;
    float4 a = *(const float4*)&ab[q * 4];
    float4 b = *(const float4*)&ab[64 + q * 4];
    float4 h = h4[idx];
    outp[idx] = make_float4(a.x * h.x + b.x, a.y * h.y + b.y, a.z * h.z + b.z,
                            a.w * h.w + b.w);
  }
}

extern "C" void kernel_launch(void* const* d_in, const int* in_sizes, int n_in,
                              void* d_out, int out_size, void* d_ws,
                              size_t ws_size, hipStream_t stream) {
  const float* x    = (const float*)d_in[0];
  const void* edges = d_in[1];
  const float* W0   = (const float*)d_in[2];
  const float* ln0w = (const float*)d_in[3];
  const float* ln0b = (const float*)d_in[4];
  const float* W1   = (const float*)d_in[5];
  const float* ln1w = (const float*)d_in[6];
  const float* ln1b = (const float*)d_in[7];
  const float* gnw  = (const float*)d_in[8];
  const float* gnb  = (const float*)d_in[9];
  const float* gna  = (const float*)d_in[10];
  const int N = in_sizes[0] / 64;
  const int E = in_sizes[1] / 2;
  const int PB1 = (E + BE1 - 1) / BE1;      // 391 radix-1 blocks
  const int HB  = (N * 8 + 511) / 512;      // 782 fp16-convert blocks
  const int nsb = (N + 1023) >> 10;         // 49 super-buckets
  const int nfb = nsb * 32;                 // 1568 final buckets

  // workspace layout (~35 MB)
  float* h         = (float*)d_ws;                                // N*64 f32
  uint4* xh8       = (uint4*)(h + (size_t)N * 64);                // N*8 uint4
  uint32_t* pairs1 = (uint32_t*)(xh8 + (size_t)N * 8);            // PB1*NSB*CAP1R
  int* counts1     = (int*)(pairs1 + (size_t)PB1 * NSB * CAP1R);  // NSB*PB1
  uint32_t* pairs2 = (uint32_t*)(counts1 + (size_t)NSB * PB1);    // NFBA*SLAB2
  int* cursors2    = (int*)(pairs2 + (size_t)NFBA * SLAB2);       // NFBA
  float* accum     = (float*)(cursors2 + NFBA);                   // NSLOT*128

  k_sort1_half<<<PB1 + HB, 512, 0, stream>>>(
      (const uint32_t*)edges, E, PB1, x, xh8, N * 8, cursors2,
      NFBA + NSLOT * 128, counts1, pairs1);
  k_part2<<<nsb * CH2, 512, 0, stream>>>(pairs1, counts1, PB1, cursors2,
                                         pairs2);
  k_fused<<<nfb, 256, 0, stream>>>((const float4*)x, xh8, pairs2, cursors2,
                                   W0, ln0w, ln0b, W1, ln1w, ln1b, h, N,
                                   accum);
  k_apply<<<(N * 16 + 255) / 256, 256, 0, stream>>>((const float4*)h, accum,
                                                    gna, gnw, gnb,
                                                    (float4*)d_out, N);
}

// Round 8
// 123.414 us; speedup vs baseline: 1.1510x; 1.1510x over previous
//
#include <hip/hip_runtime.h>
#include <hip/hip_fp16.h>
#include <stdint.h>

#define LN_EPS 1e-5f
#define GN_EPS 1e-5f

// Edge packing: (src << 16) | dst — valid because N = 50000 < 65536.
#define NSB 64        // pass-1 bins: dst>>10 (1024 nodes); 49 used at N=50000
#define BE1 2048      // edges per radix block
#define CAP1R 88      // per (block,bin) region cap (mean 42, +7.2 sigma)
#define RPC 22        // regions per part2 chunk (22*88=1936 <= 2048 stage)
#define CH2 18        // part2 chunks per super-bucket (18*22 >= 391 regions)
#define NPB2 32       // nodes per final bucket
#define SLAB2 768     // final bucket capacity (mean 510, +11 sigma)
#define NFBA 2048     // final-bucket allocation (1568 used)
#define CAP2 768
#define NSLOT 16      // GN accumulation slots

typedef _Float16 f16x8 __attribute__((ext_vector_type(8)));
typedef _Float16 f16x4 __attribute__((ext_vector_type(4)));
typedef float f32x4 __attribute__((ext_vector_type(4)));

// ---------- K1: merged {regioned radix pass 1} ∥ {x->fp16} ∥ {zero+Wcvt} ----
__global__ __launch_bounds__(512) void k_sort1_half(
    const uint32_t* __restrict__ ew, int E, int PB1,
    const float* __restrict__ x, uint4* __restrict__ xh8, int n8,
    int* __restrict__ zbase, int nz, const float* __restrict__ W0g,
    const float* __restrict__ W1g, _Float16* __restrict__ whg,
    int* __restrict__ counts1, uint32_t* __restrict__ pairs1) {
  __shared__ int whist[8 * NSB];
  __shared__ int wbase[8 * NSB];
  __shared__ int wlcur[8 * NSB];
  __shared__ int binStart[NSB];
  __shared__ uint32_t stage[BE1];  // 8KB
  const int t = threadIdx.x;

  if (blockIdx.x >= PB1) {  // ---- fp16-convert role ----
    if (blockIdx.x == PB1) {  // zero cursors2+accum; convert W0|W1 -> fp16
      for (int i = t; i < nz; i += 512) zbase[i] = 0;
      for (int i = t; i < 8192; i += 512)
        whg[i] = (_Float16)((i < 4096) ? W0g[i] : W1g[i - 4096]);
    }
    int i = (blockIdx.x - PB1) * 512 + t;
    if (i >= n8) return;
    float4 a = *(const float4*)&x[i * 8];
    float4 b = *(const float4*)&x[i * 8 + 4];
    __half2 h0 = __floats2half2_rn(a.x, a.y);
    __half2 h1 = __floats2half2_rn(a.z, a.w);
    __half2 h2 = __floats2half2_rn(b.x, b.y);
    __half2 h3 = __floats2half2_rn(b.z, b.w);
    uint4 o;
    o.x = *(uint32_t*)&h0; o.y = *(uint32_t*)&h1;
    o.z = *(uint32_t*)&h2; o.w = *(uint32_t*)&h3;
    xh8[i] = o;
    return;
  }

  // ---- radix pass-1 role ----
  const int b = blockIdx.x;
  const int w = t >> 6;
  const int e0 = b * BE1;
  const int cnt = min(BE1, E - e0);

  // Sampled dtype detect (512 odd dwords): int64 high words are always 0;
  // int32 payload (random node ids) is ~surely nonzero across 512 samples.
  uint32_t v = 0;
  if (t < cnt) v = ew[2 * (e0 + t) + 1];
  const int is32 = __syncthreads_or((int)(v != 0));

  whist[t] = 0;  // 8*NSB == 512 == blockDim
  wlcur[t] = 0;
  __syncthreads();

  uint32_t myP[4];
  #pragma unroll
  for (int r = 0; r < 4; ++r) {
    int i = t + 512 * r;
    if (i < cnt) {
      long long e = e0 + i;
      int s, d;
      if (is32) {
        s = ((const int*)ew)[e];
        d = ((const int*)ew)[(long long)E + e];
      } else {
        s = (int)((const long long*)ew)[e];
        d = (int)((const long long*)ew)[(long long)E + e];
      }
      myP[r] = ((uint32_t)s << 16) | (uint32_t)d;
      atomicAdd(&whist[w * NSB + (d >> 10)], 1);
    }
  }
  __syncthreads();

  if (t < NSB) {  // bin t: prefix over 8 waves, then wave-wide shfl scan
    int sum = 0;
    #pragma unroll
    for (int w2 = 0; w2 < 8; ++w2) {
      wbase[w2 * NSB + t] = sum;
      sum += whist[w2 * NSB + t];
    }
    int s = sum;
    #pragma unroll
    for (int d = 1; d < NSB; d <<= 1) {
      int o = __shfl_up(s, d, 64);
      if (t >= d) s += o;
    }
    binStart[t] = s - sum;
    counts1[t * PB1 + b] = sum;  // transposed: [bin][block]
  }
  __syncthreads();

  #pragma unroll
  for (int r = 0; r < 4; ++r) {
    int i = t + 512 * r;
    if (i < cnt) {
      int b2 = (int)(myP[r] & 0xFFFFu) >> 10;
      int p = binStart[b2] + wbase[w * NSB + b2] +
              atomicAdd(&wlcur[w * NSB + b2], 1);
      stage[p] = myP[r];
    }
  }
  __syncthreads();

  // coalesced write-out into fixed regions: ~42-edge runs per bin
  for (int i = t; i < cnt; i += 512) {
    uint32_t pr = stage[i];
    int sb = (int)(pr & 0xFFFFu) >> 10;
    int rel = i - binStart[sb];
    if (rel < CAP1R) pairs1[((size_t)b * NSB + sb) * CAP1R + rel] = pr;
  }
}

// ------ K2: radix pass 2 (regioned input) -> 32-node final buckets ----------
__global__ __launch_bounds__(512) void k_part2(
    const uint32_t* __restrict__ pairs1, const int* __restrict__ counts1,
    int PB1, int* cursors2, uint32_t* pairs2) {
  __shared__ int whist[8 * 32];
  __shared__ int wbase[8 * 32];
  __shared__ int wlcur[8 * 32];
  __shared__ int binStart[32], baseG[32];
  __shared__ int cLDS[RPC];
  __shared__ int totLDS;
  __shared__ uint32_t stage[BE1];  // 8KB
  const int t = threadIdx.x;
  const int w = t >> 6;
  const int sb = blockIdx.x / CH2;
  const int ch = blockIdx.x % CH2;
  const int r0 = ch * RPC;
  const int nr = min(RPC, PB1 - r0);

  if (t < 8 * 32) { whist[t] = 0; wlcur[t] = 0; }
  if (t < nr) cLDS[t] = counts1[sb * PB1 + r0 + t];
  __syncthreads();

  uint32_t myP[4];
  int myV[4];
  #pragma unroll
  for (int r = 0; r < 4; ++r) {
    int i = t + 512 * r;
    myV[r] = 0;
    if (i < nr * CAP1R) {
      int reg = i / CAP1R, idx = i % CAP1R;
      if (idx < cLDS[reg]) {
        myP[r] = pairs1[((size_t)(r0 + reg) * NSB + sb) * CAP1R + idx];
        myV[r] = 1;
        atomicAdd(&whist[(w << 5) + ((myP[r] >> 5) & 31)], 1);
      }
    }
  }
  __syncthreads();

  if (t < 32) {
    int sum = 0;
    #pragma unroll
    for (int w2 = 0; w2 < 8; ++w2) {
      wbase[(w2 << 5) + t] = sum;
      sum += whist[(w2 << 5) + t];
    }
    int s = sum;
    #pragma unroll
    for (int d = 1; d < 32; d <<= 1) {
      int o = __shfl_up(s, d, 32);
      if (t >= d) s += o;
    }
    binStart[t] = s - sum;
    baseG[t] = (sum > 0) ? atomicAdd(&cursors2[(sb << 5) + t], sum) : 0;
    if (t == 31) totLDS = s;
  }
  __syncthreads();

  #pragma unroll
  for (int r = 0; r < 4; ++r) {
    if (myV[r]) {
      int b2 = (int)(myP[r] >> 5) & 31;
      int p = binStart[b2] + wbase[(w << 5) + b2] +
              atomicAdd(&wlcur[(w << 5) + b2], 1);
      stage[p] = myP[r];
    }
  }
  __syncthreads();

  const int total = totLDS;
  for (int i = t; i < total; i += 512) {
    uint32_t pr = stage[i];
    int sub = (int)(pr >> 5) & 31;
    int o = baseG[sub] + (i - binStart[sub]);
    if (o < SLAB2) pairs2[(size_t)((sb << 5) + sub) * SLAB2 + o] = pr;
  }
}

// ---------------- K3: fused sort + gather + MFMA MLP x2 + GN partials -------
// Round-7 lesson: VALU-GEMM rebalances only trade issue vs latency-hiding.
// This version uses v_mfma_f32_16x16x32_f16: per wave per layer = 4 MFMA +
// 4 LDS b128 A-frags + 2 global 16B B-frags (vs ~1150 VALU+LDS cyc before).
// Layouts (HW-verified, learn_hip m89/m91/m92): A[row=l&15][k=8*(l>>4)+j]
// contiguous-8 along K; B from W stored [n][k] ("B^T input"); D row=
// (l>>4)*4+reg, col=l&15. LN stays f32 via small LDS Yf round-trip.
__global__ __launch_bounds__(256, 8) void k_fused(
    const float4* __restrict__ x4, const uint4* __restrict__ xh8,
    const uint32_t* __restrict__ pairs, const int* __restrict__ cursors,
    const _Float16* __restrict__ whg, const float* __restrict__ ln0w,
    const float* __restrict__ ln0b, const float* __restrict__ ln1w,
    const float* __restrict__ ln1b, float* __restrict__ out, int N,
    float* __restrict__ accum) {
  __shared__ __align__(16) _Float16 Hh[32 * 72];  // h / y1, fp16 node-major
  __shared__ __align__(16) float Yf[32 * 68];     // MFMA D -> LN scratch
  __shared__ __align__(16) int Us[896];           // sort scratch / wsum
  int* hist = Us;            // [32]
  int* offs = Us + 32;       // [32]
  int* lcur = Us + 64;       // [32]
  int* list = Us + 96;       // [CAP2=768] -> ends at 864 <= 896
  float* wsum = (float*)Us;  // [512] epilogue phase

  const int t = threadIdx.x;
  const int B = blockIdx.x;
  const int cnt = min(cursors[B], SLAB2);
  const uint32_t* pb = pairs + (size_t)B * SLAB2;
  const int node0 = B * NPB2;

  if (t < 32) hist[t] = 0;
  __syncthreads();

  for (int i = t; i < cnt; i += 256) atomicAdd(&hist[pb[i] & 31], 1);
  __syncthreads();

  if (t < 32) {  // shfl scan over 32 bins
    int v = hist[t], s = v;
    #pragma unroll
    for (int d = 1; d < 32; d <<= 1) {
      int o = __shfl_up(s, d, 32);
      if (t >= d) s += o;
    }
    offs[t] = s - v;
    lcur[t] = s - v;
  }
  __syncthreads();

  for (int i = t; i < cnt; i += 256) {
    uint32_t p = pb[i];
    int pos = atomicAdd(&lcur[p & 31], 1);
    if (pos < CAP2) list[pos] = (int)(p >> 16);
  }
  __syncthreads();

  // gather: 8 lanes/node (q8 = channel octet), fp32 self + fp16 neighbors
  const int q8 = t & 7;
  const int nl = t >> 3;  // 0..31
  const int node = node0 + nl;
  float acc[8] = {};
  if (node < N) {
    float4 sa = x4[node * 16 + 2 * q8];
    float4 sb = x4[node * 16 + 2 * q8 + 1];
    acc[0] = sa.x; acc[1] = sa.y; acc[2] = sa.z; acc[3] = sa.w;
    acc[4] = sb.x; acc[5] = sb.y; acc[6] = sb.z; acc[7] = sb.w;
    int j = offs[nl];
    const int e = min(lcur[nl], CAP2);
    for (; j + 3 < e; j += 4) {
      uint4 v0 = xh8[list[j] * 8 + q8];
      uint4 v1 = xh8[list[j + 1] * 8 + q8];
      uint4 v2 = xh8[list[j + 2] * 8 + q8];
      uint4 v3 = xh8[list[j + 3] * 8 + q8];
      #pragma unroll
      for (int c = 0; c < 4; ++c) {
        uint32_t u0 = (&v0.x)[c], u1 = (&v1.x)[c];
        uint32_t u2 = (&v2.x)[c], u3 = (&v3.x)[c];
        float2 f0 = __half22float2(*(__half2*)&u0);
        float2 f1 = __half22float2(*(__half2*)&u1);
        float2 f2 = __half22float2(*(__half2*)&u2);
        float2 f3 = __half22float2(*(__half2*)&u3);
        acc[2 * c]     += (f0.x + f1.x) + (f2.x + f3.x);
        acc[2 * c + 1] += (f0.y + f1.y) + (f2.y + f3.y);
      }
    }
    for (; j < e; ++j) {
      uint4 v0 = xh8[list[j] * 8 + q8];
      #pragma unroll
      for (int c = 0; c < 4; ++c) {
        uint32_t u0 = (&v0.x)[c];
        float2 f0 = __half22float2(*(__half2*)&u0);
        acc[2 * c] += f0.x;
        acc[2 * c + 1] += f0.y;
      }
    }
  }

  // deposit h fp16 node-major: Hh[nl][8q8..+7] single 16B store
  {
    f16x8 hv;
    #pragma unroll
    for (int c = 0; c < 8; ++c) hv[c] = (_Float16)acc[c];
    *(f16x8*)&Hh[nl * 72 + 8 * q8] = hv;
  }
  __syncthreads();  // Hh ready; sort scratch dead

  const int l = t & 63, wv = t >> 6;   // lane, wave(= n-tile)
  const int tx = t & 15, ty = t >> 4;  // LN mapping: ch quad 4tx, nodes 2ty+j
  const int ar = l & 15, ak = (l >> 4) * 8;  // A/B frag coords

  // ================= layer 1: D = h @ W0^T via MFMA ==================
  {
    f16x8 a00 = *(f16x8*)&Hh[ar * 72 + ak];
    f16x8 a01 = *(f16x8*)&Hh[ar * 72 + 32 + ak];
    f16x8 a10 = *(f16x8*)&Hh[(ar + 16) * 72 + ak];
    f16x8 a11 = *(f16x8*)&Hh[(ar + 16) * 72 + 32 + ak];
    f16x8 b0 = *(const f16x8*)&whg[(16 * wv + ar) * 64 + ak];
    f16x8 b1 = *(const f16x8*)&whg[(16 * wv + ar) * 64 + 32 + ak];
    f32x4 d0 = {0.f, 0.f, 0.f, 0.f}, d1 = {0.f, 0.f, 0.f, 0.f};
    d0 = __builtin_amdgcn_mfma_f32_16x16x32_f16(a00, b0, d0, 0, 0, 0);
    d0 = __builtin_amdgcn_mfma_f32_16x16x32_f16(a01, b1, d0, 0, 0, 0);
    d1 = __builtin_amdgcn_mfma_f32_16x16x32_f16(a10, b0, d1, 0, 0, 0);
    d1 = __builtin_amdgcn_mfma_f32_16x16x32_f16(a11, b1, d1, 0, 0, 0);
    #pragma unroll
    for (int r = 0; r < 4; ++r) {
      Yf[((l >> 4) * 4 + r) * 68 + 16 * wv + ar] = d0[r];
      Yf[((l >> 4) * 4 + r + 16) * 68 + 16 * wv + ar] = d1[r];
    }
  }
  __syncthreads();  // Yf ready

  // ---- layer-1 LN + ReLU (f32 from Yf) -> y1 fp16 into Hh ----
  {
    const float4 lw = *(const float4*)&ln0w[4 * tx];
    const float4 lb = *(const float4*)&ln0b[4 * tx];
    #pragma unroll
    for (int j = 0; j < 2; ++j) {
      float4 v = *(const float4*)&Yf[(2 * ty + j) * 68 + 4 * tx];
      float s = v.x + v.y + v.z + v.w;
      #pragma unroll
      for (int m = 1; m < 16; m <<= 1) s += __shfl_xor(s, m, 16);
      float mu = s * (1.f / 64.f);
      float d0 = v.x - mu, d1 = v.y - mu, d2 = v.z - mu, d3 = v.w - mu;
      float vv = d0 * d0 + d1 * d1 + d2 * d2 + d3 * d3;
      #pragma unroll
      for (int m = 1; m < 16; m <<= 1) vv += __shfl_xor(vv, m, 16);
      float rs = rsqrtf(vv * (1.f / 64.f) + LN_EPS);
      f16x4 yv;
      yv[0] = (_Float16)fmaxf(d0 * rs * lw.x + lb.x, 0.f);
      yv[1] = (_Float16)fmaxf(d1 * rs * lw.y + lb.y, 0.f);
      yv[2] = (_Float16)fmaxf(d2 * rs * lw.z + lb.z, 0.f);
      yv[3] = (_Float16)fmaxf(d3 * rs * lw.w + lb.w, 0.f);
      *(f16x4*)&Hh[(2 * ty + j) * 72 + 4 * tx] = yv;
    }
  }
  __syncthreads();  // Hh = y1 ready

  // ================= layer 2: D = y1 @ W1^T via MFMA =================
  {
    f16x8 a00 = *(f16x8*)&Hh[ar * 72 + ak];
    f16x8 a01 = *(f16x8*)&Hh[ar * 72 + 32 + ak];
    f16x8 a10 = *(f16x8*)&Hh[(ar + 16) * 72 + ak];
    f16x8 a11 = *(f16x8*)&Hh[(ar + 16) * 72 + 32 + ak];
    f16x8 b0 = *(const f16x8*)&whg[4096 + (16 * wv + ar) * 64 + ak];
    f16x8 b1 = *(const f16x8*)&whg[4096 + (16 * wv + ar) * 64 + 32 + ak];
    f32x4 d0 = {0.f, 0.f, 0.f, 0.f}, d1 = {0.f, 0.f, 0.f, 0.f};
    d0 = __builtin_amdgcn_mfma_f32_16x16x32_f16(a00, b0, d0, 0, 0, 0);
    d0 = __builtin_amdgcn_mfma_f32_16x16x32_f16(a01, b1, d0, 0, 0, 0);
    d1 = __builtin_amdgcn_mfma_f32_16x16x32_f16(a10, b0, d1, 0, 0, 0);
    d1 = __builtin_amdgcn_mfma_f32_16x16x32_f16(a11, b1, d1, 0, 0, 0);
    __syncthreads();  // LN1 Yf reads done before overwrite
    #pragma unroll
    for (int r = 0; r < 4; ++r) {
      Yf[((l >> 4) * 4 + r) * 68 + 16 * wv + ar] = d0[r];
      Yf[((l >> 4) * 4 + r + 16) * 68 + 16 * wv + ar] = d1[r];
    }
  }
  __syncthreads();  // Yf = pre-LN2 ready

  // ---- layer-2 LN + ReLU + store h + GraphNorm partials ----
  const float4 lw = *(const float4*)&ln1w[4 * tx];
  const float4 lb = *(const float4*)&ln1b[4 * tx];
  float st1[4] = {0.f, 0.f, 0.f, 0.f}, st2[4] = {0.f, 0.f, 0.f, 0.f};
  #pragma unroll
  for (int j = 0; j < 2; ++j) {
    int nodej = node0 + 2 * ty + j;
    float4 v = *(const float4*)&Yf[(2 * ty + j) * 68 + 4 * tx];
    float s = v.x + v.y + v.z + v.w;
    #pragma unroll
    for (int m = 1; m < 16; m <<= 1) s += __shfl_xor(s, m, 16);
    float mu = s * (1.f / 64.f);
    float d0 = v.x - mu, d1 = v.y - mu, d2 = v.z - mu, d3 = v.w - mu;
    float vv = d0 * d0 + d1 * d1 + d2 * d2 + d3 * d3;
    #pragma unroll
    for (int m = 1; m < 16; m <<= 1) vv += __shfl_xor(vv, m, 16);
    float rs = rsqrtf(vv * (1.f / 64.f) + LN_EPS);
    float y0 = fmaxf(d0 * rs * lw.x + lb.x, 0.f);
    float y1 = fmaxf(d1 * rs * lw.y + lb.y, 0.f);
    float y2 = fmaxf(d2 * rs * lw.z + lb.z, 0.f);
    float y3 = fmaxf(d3 * rs * lw.w + lb.w, 0.f);
    if (nodej < N) {
      *(float4*)&out[(long long)nodej * 64 + 4 * tx] =
          make_float4(y0, y1, y2, y3);
      st1[0] += y0; st2[0] += y0 * y0;
      st1[1] += y1; st2[1] += y1 * y1;
      st1[2] += y2; st2[2] += y2 * y2;
      st1[3] += y3; st2[3] += y3 * y3;
    }
  }
  #pragma unroll
  for (int i = 0; i < 4; ++i) {
    st1[i] += __shfl_xor(st1[i], 16, 64); st1[i] += __shfl_xor(st1[i], 32, 64);
    st2[i] += __shfl_xor(st2[i], 16, 64); st2[i] += __shfl_xor(st2[i], 32, 64);
  }
  __syncthreads();  // Us (wsum alias) free; Yf reads done
  const int lane = t & 63, w = t >> 6;
  if (lane < 16) {
    #pragma unroll
    for (int i = 0; i < 4; ++i) {
      wsum[w * 128 + 4 * lane + i] = st1[i];
      wsum[w * 128 + 64 + 4 * lane + i] = st2[i];
    }
  }
  __syncthreads();
  if (t < 128) {
    float s = wsum[t] + wsum[128 + t] + wsum[256 + t] + wsum[384 + t];
    // slotted device-scope accumulation; visibility via stream order
    atomicAdd(&accum[(B & (NSLOT - 1)) * 128 + t], s);
  }
}

// -------- K4: per-block ab = f(slot sums) (L2-resident), then apply ---------
__global__ __launch_bounds__(256) void k_apply(
    const float4* __restrict__ h4, const float* __restrict__ accum,
    const float* __restrict__ alpha, const float* __restrict__ gnw,
    const float* __restrict__ gnb, float4* __restrict__ outp, int N) {
  __shared__ float cs[128];  // column sums: [0..63]=Σy, [64..127]=Σy²
  __shared__ float ab[128];  // [0..63]=a, [64..127]=b
  const int t = threadIdx.x;
  if (t < 128) {
    float s = 0.f;
    #pragma unroll
    for (int sl = 0; sl < NSLOT; ++sl) s += accum[sl * 128 + t];
    cs[t] = s;
  }
  __syncthreads();
  if (t < 64) {
    float invN = 1.f / (float)N;
    float mu = cs[t] * invN;
    float e2 = cs[64 + t] * invN;
    float al = alpha[t];
    float var = e2 - 2.f * al * mu * mu + al * al * mu * mu;
    float a = gnw[t] * rsqrtf(var + GN_EPS);
    ab[t] = a;
    ab[64 + t] = gnb[t] - a * al * mu;
  }
  __syncthreads();
  int idx = blockIdx.x * 256 + t;
  if (idx < N * 16) {
    int q = idx & 15;
    float4 a = *(const float4*)&ab[q * 4];
    float4 b = *(const float4*)&ab[64 + q * 4];
    float4 h = h4[idx];
    outp[idx] = make_float4(a.x * h.x + b.x, a.y * h.y + b.y, a.z * h.z + b.z,
                            a.w * h.w + b.w);
  }
}

extern "C" void kernel_launch(void* const* d_in, const int* in_sizes, int n_in,
                              void* d_out, int out_size, void* d_ws,
                              size_t ws_size, hipStream_t stream) {
  const float* x    = (const float*)d_in[0];
  const void* edges = d_in[1];
  const float* W0   = (const float*)d_in[2];
  const float* ln0w = (const float*)d_in[3];
  const float* ln0b = (const float*)d_in[4];
  const float* W1   = (const float*)d_in[5];
  const float* ln1w = (const float*)d_in[6];
  const float* ln1b = (const float*)d_in[7];
  const float* gnw  = (const float*)d_in[8];
  const float* gnb  = (const float*)d_in[9];
  const float* gna  = (const float*)d_in[10];
  const int N = in_sizes[0] / 64;
  const int E = in_sizes[1] / 2;
  const int PB1 = (E + BE1 - 1) / BE1;      // 391 radix-1 blocks
  const int HB  = (N * 8 + 511) / 512;      // 782 fp16-convert blocks
  const int nsb = (N + 1023) >> 10;         // 49 super-buckets
  const int nfb = nsb * 32;                 // 1568 final buckets

  // workspace layout (~35 MB)
  float* h         = (float*)d_ws;                                // N*64 f32
  uint4* xh8       = (uint4*)(h + (size_t)N * 64);                // N*8 uint4
  uint32_t* pairs1 = (uint32_t*)(xh8 + (size_t)N * 8);            // PB1*NSB*CAP1R
  int* counts1     = (int*)(pairs1 + (size_t)PB1 * NSB * CAP1R);  // NSB*PB1
  uint32_t* pairs2 = (uint32_t*)(counts1 + (size_t)NSB * PB1);    // NFBA*SLAB2
  int* cursors2    = (int*)(pairs2 + (size_t)NFBA * SLAB2);       // NFBA
  float* accum     = (float*)(cursors2 + NFBA);                   // NSLOT*128
  _Float16* whg    = (_Float16*)(accum + NSLOT * 128);            // 2*64*64

  k_sort1_half<<<PB1 + HB, 512, 0, stream>>>(
      (const uint32_t*)edges, E, PB1, x, xh8, N * 8, cursors2,
      NFBA + NSLOT * 128, W0, W1, whg, counts1, pairs1);
  k_part2<<<nsb * CH2, 512, 0, stream>>>(pairs1, counts1, PB1, cursors2,
                                         pairs2);
  k_fused<<<nfb, 256, 0, stream>>>((const float4*)x, xh8, pairs2, cursors2,
                                   whg, ln0w, ln0b, ln1w, ln1b, h, N, accum);
  k_apply<<<(N * 16 + 255) / 256, 256, 0, stream>>>((const float4*)h, accum,
                                                    gna, gnw, gnb,
                                                    (float4*)d_out, N);
}